// Round 8
// baseline (256.143 us; speedup 1.0000x reference)
//
#include <hip/hip_runtime.h>
#include <math.h>
#include <stdint.h>

#define B_ 2
#define N_ 512

// ws layout (float offsets)
#define WS_WBF   0            // 14976 shorts = 7488 floats, pad 7680
#define WS_NGEO  7680         // B*N*8      = 8192   {x0,x1,x2,0, qw,qx,qy,qz}
#define WS_APRE  15872        // B*N*64     = 65536  (bm1 folded in)
#define WS_BPREF 81408        // B*N*64     = 65536  (MFMA-fragment order)
#define WS_MPART 146944       // 2*B*N*64   = 131072
#define WS_DXBUF 278016       // B*N*N*4    = 2097152  (total 2375168 floats)

typedef short short8v __attribute__((ext_vector_type(8)));
typedef float f32x4 __attribute__((ext_vector_type(4)));

union FragU { int4 i; short8v s; };
union PackU { uint32_t w[4]; short8v s; };

static __device__ inline uint32_t pk2(float lo, float hi) {
    uint32_t r;
    asm volatile("v_cvt_pk_bf16_f32 %0, %1, %2" : "=v"(r) : "v"(lo), "v"(hi));
    return r;
}
static __device__ inline short f2bs(float f) {  // RNE f32->bf16
    uint32_t u = __float_as_uint(f);
    u = (u + 0x7FFFu + ((u >> 16) & 1u)) >> 16;
    return (short)u;
}

// ---------------------------------------------------------------------------
// Kernel P: one-time weight permute+bf16 into ws (layout == k_edge LDS):
//   [0,4608)=W1', [4608,9216)=W2', [9216,13824)=W3', [13824,14976)=W4'
// grid: 23 blocks x 256
// ---------------------------------------------------------------------------
__global__ void k_prep(const float* __restrict__ Wm1, const float* __restrict__ Wm2,
                       const float* __restrict__ Wt1, const float* __restrict__ Wt2,
                       short* __restrict__ wbf)
{
    const int id = blockIdx.x * 256 + threadIdx.x;
    if (id < 4608) {
        const int ch = id / 72, p = id % 72;
        float v1 = 0.f, v2 = 0.f, v3 = 0.f;
        if (p < 64) {
            if (p < 32) v1 = Wm1[(128 + p) * 64 + ch];
            else if (p < 41) v1 = Wm1[(160 + p - 32) * 64 + ch];
            const int s = p >> 5, ee = p & 7, gg = (p >> 3) & 3;
            const int k1 = 32 * s + 16 * (ee >> 2) + 4 * gg + (ee & 3);
            v2 = Wm2[k1 * 64 + ch];
            v3 = Wt1[k1 * 64 + ch];
        }
        wbf[id] = f2bs(v1);
        wbf[4608 + id] = f2bs(v2);
        wbf[9216 + id] = f2bs(v3);
    } else if (id < 5760) {
        const int idx = id - 4608;
        const int d = idx / 72, p = idx % 72;
        float v = 0.f;
        if (p < 64 && d < 3) {
            const int s = p >> 5, ee = p & 7, gg = (p >> 3) & 3;
            const int k1 = 32 * s + 16 * (ee >> 2) + 4 * gg + (ee & 3);
            v = Wt2[k1 * 3 + d];
        }
        wbf[13824 + idx] = f2bs(v);
    }
}

// ---------------------------------------------------------------------------
// Kernel 0: per-node precompute (unchanged from round 7).
// ---------------------------------------------------------------------------
__global__ __launch_bounds__(256) void k_node_pre(
    const float* __restrict__ x,
    const float* __restrict__ quats,
    const float* __restrict__ h,
    const float* __restrict__ Wm1,
    const float* __restrict__ bm1,
    float* __restrict__ ngeo,
    float* __restrict__ Apre,
    float* __restrict__ BpreF)
{
    __shared__ float sW[128 * 64];
    __shared__ float sh[4][64];

    const int tid = threadIdx.x;
    for (int idx = tid; idx < 128 * 64 / 4; idx += 256)
        ((float4*)sW)[idx] = ((const float4*)Wm1)[idx];

    const int wv = tid >> 6;
    const int c = tid & 63;
    const int node = blockIdx.x * 4 + wv;

    sh[wv][c] = h[node * 64 + c];
    __syncthreads();

    float a = bm1[c];
    float bv = 0.f;
#pragma unroll 8
    for (int k = 0; k < 64; ++k) {
        const float hk = sh[wv][k];
        a  = fmaf(hk, sW[k * 64 + c], a);
        bv = fmaf(hk, sW[(64 + k) * 64 + c], bv);
    }
    Apre[node * 64 + c] = a;
    const int aa = c >> 4, gg = (c >> 2) & 3, bb = c & 3;
    BpreF[(node >> 4) * 1024 + ((node & 15) + 16 * gg) * 16 + 4 * aa + bb] = bv;

    if (c == 0) {
        ngeo[node * 8 + 0] = x[node * 3 + 0];
        ngeo[node * 8 + 1] = x[node * 3 + 1];
        ngeo[node * 8 + 2] = x[node * 3 + 2];
        ngeo[node * 8 + 3] = 0.f;
        ngeo[node * 8 + 4] = quats[node * 4 + 0];
        ngeo[node * 8 + 5] = quats[node * 4 + 1];
        ngeo[node * 8 + 6] = quats[node * 4 + 2];
        ngeo[node * 8 + 7] = quats[node * 4 + 3];
    }
}

// ---------------------------------------------------------------------------
// Kernel A: MFMA edge pipeline. 512 blocks x 512 threads (8 waves).
// Block (ig, half): nodes ig*4..ig*4+3; wave w: node ig*4+(w>>1),
// quarter = half*2+(w&1), 8 tiles of 16 j. Weights: flat copy from wbf.
// ---------------------------------------------------------------------------
__global__ __launch_bounds__(512, 4) void k_edge(
    const float* __restrict__ e,
    const float* __restrict__ ngeo,
    const float* __restrict__ Apre,
    const float* __restrict__ BpreF,
    const short* __restrict__ wbf,
    const float* __restrict__ bm2,
    const float* __restrict__ bt1,
    const float* __restrict__ bt2,
    float* __restrict__ mpart, float* __restrict__ dxbuf)
{
    __shared__ __align__(16) short Ws[14976];
    __shared__ float msLDS[4][64];

    const int tid = threadIdx.x;

    for (int idx = tid; idx < 1872; idx += 512)
        ((int4*)Ws)[idx] = ((const int4*)wbf)[idx];
    __syncthreads();

    const short* W1s = Ws;
    const short* W2s = Ws + 4608;
    const short* W3s = Ws + 9216;
    const short* W4s = Ws + 13824;

    const int w = tid >> 6;
    const int l = tid & 63;
    const int g = l >> 4;
    const int c = l & 15;

    const int ig = blockIdx.x >> 1;
    const int half = blockIdx.x & 1;
    const int ni = ig * 4 + (w >> 1);   // 0..1023
    const int b = ni >> 9;
    const int i = ni & 511;
    const int quarter = half * 2 + (w & 1);
    const int j0w = quarter * 128;

    // i-node data
    const float4 gi0 = ((const float4*)ngeo)[ni * 2 + 0];
    const float4 gi1 = ((const float4*)ngeo)[ni * 2 + 1];
    const float xi0 = gi0.x, xi1 = gi0.y, xi2 = gi0.z;
    const float qi0 = gi1.x, qi1 = gi1.y, qi2 = gi1.z, qi3 = gi1.w;

    float apre[16], bm2r[16], bt1r[16], bt2r[4];
#pragma unroll
    for (int q = 0; q < 16; ++q) {
        const int row = 16 * (q >> 2) + 4 * g + (q & 3);
        apre[q] = Apre[ni * 64 + row];
        bm2r[q] = bm2[row];
        bt1r[q] = bt1[row];
    }
#pragma unroll
    for (int q = 0; q < 4; ++q) {
        const int d = 4 * g + q;
        bt2r[q] = (d < 3) ? bt2[d] : 0.f;
    }

    float msum[16];
#pragma unroll
    for (int q = 0; q < 16; ++q) msum[q] = 0.f;

#pragma unroll 2
    for (int t = 0; t < 8; ++t) {
        const int j0m = j0w + t * 16;
        const int nj = b * N_ + j0m + c;

        // ---- all global loads issued up front ----
        const float* ep = e + ((size_t)(b * N_ + i) * N_ + j0m + c) * 32 + g * 8;
        const float4 e0 = *(const float4*)ep;
        const float4 e1 = *(const float4*)(ep + 4);
        const float4 n0 = ((const float4*)ngeo)[nj * 2 + 0];
        const float4 n1 = ((const float4*)ngeo)[nj * 2 + 1];
        const float* bp = BpreF + (size_t)(nj >> 4) * 1024 + l * 16;
        const float4 bi0 = ((const float4*)bp)[0];
        const float4 bi1 = ((const float4*)bp)[1];
        const float4 bi2 = ((const float4*)bp)[2];
        const float4 bi3 = ((const float4*)bp)[3];

        // ---- geometry for edge (i, j0m+c), in registers ----
        const float xj0 = n0.x, xj1 = n0.y, xj2 = n0.z;
        const float qj0 = n1.x, qj1 = n1.y, qj2 = n1.z, qj3 = n1.w;
        const float dsum = qj0 * qj0 + qj1 * qj1 + qj2 * qj2 + qj3 * qj3;
        const float inv = __builtin_amdgcn_rcpf(dsum);
        const float qw = qj0 * inv, qx = -qj1 * inv;
        const float qy = -qj2 * inv, qz = -qj3 * inv;
        const float d0 = xi0 - xj0, d1 = xi1 - xj1, d2v = xi2 - xj2;
        const float dd = d0 * d0 + d1 * d1 + d2v * d2v;
        const float qd = fabsf(qi0 * qj0 + qi1 * qj1 + qi2 * qj2 + qi3 * qj3);
        const float ww = qw * qw, xx = qx * qx, yy = qy * qy, zz = qz * qz;
        const float xy = qx * qy, xz = qx * qz, yz = qy * qz;
        const float wx = qw * qx, wy = qw * qy, wz = qw * qz;
        const float lx0 = (ww + xx - yy - zz) * d0 + 2.f * (xy - wz) * d1 + 2.f * (xz + wy) * d2v;
        const float lx1 = 2.f * (xy + wz) * d0 + (ww - xx + yy - zz) * d1 + 2.f * (yz - wx) * d2v;
        const float lx2 = 2.f * (xz - wy) * d0 + 2.f * (yz + wx) * d1 + (ww - xx - yy + zz) * d2v;
        const float lq0 = qw * qi0 - qx * qi1 - qy * qi2 - qz * qi3;
        const float lq1 = qw * qi1 + qx * qi0 + qy * qi3 - qz * qi2;
        const float lq2 = qw * qi2 - qx * qi3 + qy * qi0 + qz * qi1;
        const float lq3 = qw * qi3 + qx * qi2 - qy * qi1 + qz * qi0;

        // ---- build S1 B-operand frags in registers ----
        PackU y0, yg;
        y0.w[0] = pk2(e0.x, e0.y); y0.w[1] = pk2(e0.z, e0.w);
        y0.w[2] = pk2(e1.x, e1.y); y0.w[3] = pk2(e1.z, e1.w);
        const uint32_t w0 = pk2(lx0, lx1), w1 = pk2(lx2, lq0);
        const uint32_t w2 = pk2(lq1, lq2), w3 = pk2(lq3, dd);
        const uint32_t wq = pk2(qd, 0.f);
        yg.w[0] = (g == 0) ? w0 : ((g == 1) ? wq : 0u);
        yg.w[1] = (g == 0) ? w1 : 0u;
        yg.w[2] = (g == 0) ? w2 : 0u;
        yg.w[3] = (g == 0) ? w3 : 0u;

        // ---- S1: m1T = relu(W1' x feat + Apre + Bpre) ----
        f32x4 acc1[4];
        acc1[0][0] = apre[0] + bi0.x;  acc1[0][1] = apre[1] + bi0.y;
        acc1[0][2] = apre[2] + bi0.z;  acc1[0][3] = apre[3] + bi0.w;
        acc1[1][0] = apre[4] + bi1.x;  acc1[1][1] = apre[5] + bi1.y;
        acc1[1][2] = apre[6] + bi1.z;  acc1[1][3] = apre[7] + bi1.w;
        acc1[2][0] = apre[8] + bi2.x;  acc1[2][1] = apre[9] + bi2.y;
        acc1[2][2] = apre[10] + bi2.z; acc1[2][3] = apre[11] + bi2.w;
        acc1[3][0] = apre[12] + bi3.x; acc1[3][1] = apre[13] + bi3.y;
        acc1[3][2] = apre[14] + bi3.z; acc1[3][3] = apre[15] + bi3.w;
#pragma unroll
        for (int nt = 0; nt < 4; ++nt) {
            FragU xw0, xw1;
            xw0.i = *(const int4*)&W1s[(16 * nt + c) * 72 + g * 8];
            xw1.i = *(const int4*)&W1s[(16 * nt + c) * 72 + 32 + g * 8];
            acc1[nt] = __builtin_amdgcn_mfma_f32_16x16x32_bf16(xw0.s, y0.s, acc1[nt], 0, 0, 0);
            acc1[nt] = __builtin_amdgcn_mfma_f32_16x16x32_bf16(xw1.s, yg.s, acc1[nt], 0, 0, 0);
        }

        PackU by1[2];
#pragma unroll
        for (int s = 0; s < 2; ++s) {
            const f32x4 a0 = acc1[2 * s], a1 = acc1[2 * s + 1];
            by1[s].w[0] = pk2(fmaxf(a0[0], 0.f), fmaxf(a0[1], 0.f));
            by1[s].w[1] = pk2(fmaxf(a0[2], 0.f), fmaxf(a0[3], 0.f));
            by1[s].w[2] = pk2(fmaxf(a1[0], 0.f), fmaxf(a1[1], 0.f));
            by1[s].w[3] = pk2(fmaxf(a1[2], 0.f), fmaxf(a1[3], 0.f));
        }

        // ---- S2: mT = W2' x m1 + bm2 ----
        f32x4 acc2[4];
#pragma unroll
        for (int nt = 0; nt < 4; ++nt) {
            acc2[nt][0] = bm2r[nt * 4 + 0]; acc2[nt][1] = bm2r[nt * 4 + 1];
            acc2[nt][2] = bm2r[nt * 4 + 2]; acc2[nt][3] = bm2r[nt * 4 + 3];
        }
#pragma unroll
        for (int nt = 0; nt < 4; ++nt)
#pragma unroll
            for (int s = 0; s < 2; ++s) {
                FragU xw;
                xw.i = *(const int4*)&W2s[(16 * nt + c) * 72 + s * 32 + g * 8];
                acc2[nt] = __builtin_amdgcn_mfma_f32_16x16x32_bf16(
                    xw.s, by1[s].s, acc2[nt], 0, 0, 0);
            }

        const float maskf = (j0m + c == i) ? 0.f : 1.f;
#pragma unroll
        for (int nt = 0; nt < 4; ++nt) {
            acc2[nt][0] *= maskf; acc2[nt][1] *= maskf;
            acc2[nt][2] *= maskf; acc2[nt][3] *= maskf;
            msum[nt * 4 + 0] += acc2[nt][0];
            msum[nt * 4 + 1] += acc2[nt][1];
            msum[nt * 4 + 2] += acc2[nt][2];
            msum[nt * 4 + 3] += acc2[nt][3];
        }

        PackU by2[2];
#pragma unroll
        for (int s = 0; s < 2; ++s) {
            const f32x4 a0 = acc2[2 * s], a1 = acc2[2 * s + 1];
            by2[s].w[0] = pk2(a0[0], a0[1]);
            by2[s].w[1] = pk2(a0[2], a0[3]);
            by2[s].w[2] = pk2(a1[0], a1[1]);
            by2[s].w[3] = pk2(a1[2], a1[3]);
        }

        // ---- S3: t1T = relu(W3' x m + bt1) ----
        f32x4 acc3[4];
#pragma unroll
        for (int nt = 0; nt < 4; ++nt) {
            acc3[nt][0] = bt1r[nt * 4 + 0]; acc3[nt][1] = bt1r[nt * 4 + 1];
            acc3[nt][2] = bt1r[nt * 4 + 2]; acc3[nt][3] = bt1r[nt * 4 + 3];
        }
#pragma unroll
        for (int nt = 0; nt < 4; ++nt)
#pragma unroll
            for (int s = 0; s < 2; ++s) {
                FragU xw;
                xw.i = *(const int4*)&W3s[(16 * nt + c) * 72 + s * 32 + g * 8];
                acc3[nt] = __builtin_amdgcn_mfma_f32_16x16x32_bf16(
                    xw.s, by2[s].s, acc3[nt], 0, 0, 0);
            }

        PackU by3[2];
#pragma unroll
        for (int s = 0; s < 2; ++s) {
            const f32x4 a0 = acc3[2 * s], a1 = acc3[2 * s + 1];
            by3[s].w[0] = pk2(fmaxf(a0[0], 0.f), fmaxf(a0[1], 0.f));
            by3[s].w[1] = pk2(fmaxf(a0[2], 0.f), fmaxf(a0[3], 0.f));
            by3[s].w[2] = pk2(fmaxf(a1[0], 0.f), fmaxf(a1[1], 0.f));
            by3[s].w[3] = pk2(fmaxf(a1[2], 0.f), fmaxf(a1[3], 0.f));
        }

        // ---- dx: rows 0..2 of W4' x t1 + bt2 ----
        f32x4 acc4;
        acc4[0] = bt2r[0]; acc4[1] = bt2r[1]; acc4[2] = bt2r[2]; acc4[3] = bt2r[3];
#pragma unroll
        for (int s = 0; s < 2; ++s) {
            FragU xw;
            xw.i = *(const int4*)&W4s[c * 72 + s * 32 + g * 8];
            acc4 = __builtin_amdgcn_mfma_f32_16x16x32_bf16(
                xw.s, by3[s].s, acc4, 0, 0, 0);
        }
        if (g == 0) {
            float4 o4;
            o4.x = acc4[0] * maskf; o4.y = acc4[1] * maskf;
            o4.z = acc4[2] * maskf; o4.w = 0.f;
            ((float4*)dxbuf)[(size_t)ni * N_ + j0m + c] = o4;
        }
    }

    // ---- msum: xor-reduce over c, combine wave pairs in LDS, store halves ----
#pragma unroll
    for (int q = 0; q < 16; ++q) {
        float v = msum[q];
        v += __shfl_xor(v, 1); v += __shfl_xor(v, 2);
        v += __shfl_xor(v, 4); v += __shfl_xor(v, 8);
        msum[q] = v;
    }
    __syncthreads();
    if ((w & 1) && c == 0) {
#pragma unroll
        for (int q = 0; q < 16; ++q)
            msLDS[w >> 1][16 * (q >> 2) + 4 * g + (q & 3)] = msum[q];
    }
    __syncthreads();
    if (!(w & 1) && c == 0) {
#pragma unroll
        for (int nt = 0; nt < 4; ++nt) {
            float4 mo;
            mo.x = msum[nt * 4 + 0] + msLDS[w >> 1][16 * nt + 4 * g + 0];
            mo.y = msum[nt * 4 + 1] + msLDS[w >> 1][16 * nt + 4 * g + 1];
            mo.z = msum[nt * 4 + 2] + msLDS[w >> 1][16 * nt + 4 * g + 2];
            mo.w = msum[nt * 4 + 3] + msLDS[w >> 1][16 * nt + 4 * g + 3];
            *(float4*)&mpart[((size_t)(half * (B_ * N_) + ni)) * 64 + 16 * nt + 4 * g] = mo;
        }
    }
}

// ---------------------------------------------------------------------------
// Kernel B: per-node outputs (2 mpart halves now).
// ---------------------------------------------------------------------------
__global__ __launch_bounds__(256) void k_node_post(
    const float* __restrict__ quats,
    const float* __restrict__ h,
    const float* __restrict__ mpart,
    const float* __restrict__ Wf1, const float* __restrict__ bf1,
    const float* __restrict__ Wf2, const float* __restrict__ bf2,
    const float* __restrict__ Wq1, const float* __restrict__ bq1,
    const float* __restrict__ Wq2, const float* __restrict__ bq2,
    float* __restrict__ out_q, float* __restrict__ out_o)
{
    __shared__ float sWf1[128 * 64];
    __shared__ float sWf2[64 * 64];
    __shared__ float sWq1[64 * 64];
    __shared__ float sWq2[64 * 4];
    __shared__ float sh[4][64], sm[4][64], stf[4][64], stq[4][64];

    const int tid = threadIdx.x;
    for (int idx = tid; idx < 128 * 64 / 4; idx += 256)
        ((float4*)sWf1)[idx] = ((const float4*)Wf1)[idx];
    for (int idx = tid; idx < 64 * 64 / 4; idx += 256) {
        ((float4*)sWf2)[idx] = ((const float4*)Wf2)[idx];
        ((float4*)sWq1)[idx] = ((const float4*)Wq1)[idx];
    }
    if (tid < 64) {
        sWq2[tid * 4 + 0] = Wq2[tid * 4 + 0];
        sWq2[tid * 4 + 1] = Wq2[tid * 4 + 1];
        sWq2[tid * 4 + 2] = Wq2[tid * 4 + 2];
        sWq2[tid * 4 + 3] = Wq2[tid * 4 + 3];
    }

    const int wv = tid >> 6;
    const int c = tid & 63;
    const int node = blockIdx.x * 4 + wv;

    const float ms = mpart[(size_t)node * 64 + c] +
                     mpart[((size_t)(B_ * N_) + node) * 64 + c];
    sm[wv][c] = ms;
    sh[wv][c] = h[node * 64 + c];
    __syncthreads();

    float accf = bf1[c];
    float accq = bq1[c];
#pragma unroll 8
    for (int k = 0; k < 64; ++k) {
        const float hk = sh[wv][k];
        const float mk = sm[wv][k];
        accf = fmaf(hk, sWf1[k * 64 + c], accf);
        accf = fmaf(mk, sWf1[(64 + k) * 64 + c], accf);
        accq = fmaf(mk, sWq1[k * 64 + c], accq);
    }
    stf[wv][c] = fmaxf(accf, 0.f);
    stq[wv][c] = fmaxf(accq, 0.f);
    __syncthreads();

    float o = bf2[c];
#pragma unroll 8
    for (int k = 0; k < 64; ++k) o = fmaf(stf[wv][k], sWf2[k * 64 + c], o);
    out_o[(size_t)node * 64 + c] = o;

    {
        const int d = c & 3, kb = c >> 2;
        float p = 0.f;
#pragma unroll
        for (int m = 0; m < 4; ++m) {
            const int kk = kb + 16 * m;
            p = fmaf(stq[wv][kk], sWq2[kk * 4 + d], p);
        }
        p += __shfl_xor(p, 4);  p += __shfl_xor(p, 8);
        p += __shfl_xor(p, 16); p += __shfl_xor(p, 32);
        const float p0 = __shfl(p, 0), p1 = __shfl(p, 1);
        const float p2 = __shfl(p, 2), p3 = __shfl(p, 3);
        if (c == 0) {
            float dq0 = p0 + bq2[0], dq1 = p1 + bq2[1];
            float dq2 = p2 + bq2[2], dq3 = p3 + bq2[3];
            const float nrm = sqrtf(dq0 * dq0 + dq1 * dq1 + dq2 * dq2 + dq3 * dq3);
            const float inv = 1.f / fmaxf(nrm, 1e-12f);
            const float b0 = dq0 * inv, b1 = dq1 * inv, b2 = dq2 * inv, b3 = dq3 * inv;
            const float aw = quats[node * 4 + 0], ax = quats[node * 4 + 1];
            const float ay = quats[node * 4 + 2], az = quats[node * 4 + 3];
            float u0 = aw * b0 - ax * b1 - ay * b2 - az * b3;
            float u1 = aw * b1 + ax * b0 + ay * b3 - az * b2;
            float u2 = aw * b2 - ax * b3 + ay * b0 + az * b1;
            float u3 = aw * b3 + ax * b2 - ay * b1 + az * b0;
            const float n2 = sqrtf(u0 * u0 + u1 * u1 + u2 * u2 + u3 * u3);
            u0 /= n2; u1 /= n2; u2 /= n2; u3 /= n2;
            out_q[node * 4 + 0] = u0; out_q[node * 4 + 1] = u1;
            out_q[node * 4 + 2] = u2; out_q[node * 4 + 3] = u3;
        }
    }
}

// ---------------------------------------------------------------------------
// Kernel C: upd_x[i] = x_i + (sum_j R(out_q_j) dx[i,j]) / (N-1)
// ---------------------------------------------------------------------------
__global__ void k_aggregate(const float* __restrict__ x,
                            const float* __restrict__ out_q,
                            const float* __restrict__ dxbuf,
                            float* __restrict__ out_x)
{
    const int node = blockIdx.x;
    const int b = node >> 9;
    const int tid = threadIdx.x;

    float s0 = 0.f, s1 = 0.f, s2 = 0.f;
    for (int j = tid; j < N_; j += 256) {
        const float4 d4 = ((const float4*)dxbuf)[(size_t)node * N_ + j];
        const float4 q4 = ((const float4*)out_q)[b * N_ + j];
        const float w = q4.x, X = q4.y, Y = q4.z, Z = q4.w;
        const float ww = w * w, xx = X * X, yy = Y * Y, zz = Z * Z;
        const float xy = X * Y, xz = X * Z, yz = Y * Z;
        const float wx = w * X, wy = w * Y, wz = w * Z;
        s0 += (ww + xx - yy - zz) * d4.x + 2.f * (xy - wz) * d4.y + 2.f * (xz + wy) * d4.z;
        s1 += 2.f * (xy + wz) * d4.x + (ww - xx + yy - zz) * d4.y + 2.f * (yz - wx) * d4.z;
        s2 += 2.f * (xz - wy) * d4.x + 2.f * (yz + wx) * d4.y + (ww - xx - yy + zz) * d4.z;
    }
#pragma unroll
    for (int off = 1; off <= 32; off <<= 1) {
        s0 += __shfl_xor(s0, off);
        s1 += __shfl_xor(s1, off);
        s2 += __shfl_xor(s2, off);
    }
    __shared__ float red[4][3];
    const int wave = tid >> 6, lane = tid & 63;
    if (lane == 0) { red[wave][0] = s0; red[wave][1] = s1; red[wave][2] = s2; }
    __syncthreads();
    if (tid == 0) {
        const float t0 = red[0][0] + red[1][0] + red[2][0] + red[3][0];
        const float t1 = red[0][1] + red[1][1] + red[2][1] + red[3][1];
        const float t2 = red[0][2] + red[1][2] + red[2][2] + red[3][2];
        const float inv = 1.f / (float)(N_ - 1);
        out_x[node * 3 + 0] = x[node * 3 + 0] + t0 * inv;
        out_x[node * 3 + 1] = x[node * 3 + 1] + t1 * inv;
        out_x[node * 3 + 2] = x[node * 3 + 2] + t2 * inv;
    }
}

// ---------------------------------------------------------------------------
extern "C" void kernel_launch(void* const* d_in, const int* in_sizes, int n_in,
                              void* d_out, int out_size, void* d_ws, size_t ws_size,
                              hipStream_t stream) {
    const float* x     = (const float*)d_in[0];
    const float* quats = (const float*)d_in[1];
    const float* h     = (const float*)d_in[2];
    const float* e     = (const float*)d_in[3];
    const float* Wm1 = (const float*)d_in[5];
    const float* bm1 = (const float*)d_in[6];
    const float* Wm2 = (const float*)d_in[7];
    const float* bm2 = (const float*)d_in[8];
    const float* Wf1 = (const float*)d_in[9];
    const float* bf1 = (const float*)d_in[10];
    const float* Wf2 = (const float*)d_in[11];
    const float* bf2 = (const float*)d_in[12];
    const float* Wt1 = (const float*)d_in[13];
    const float* bt1 = (const float*)d_in[14];
    const float* Wt2 = (const float*)d_in[15];
    const float* bt2 = (const float*)d_in[16];
    const float* Wq1 = (const float*)d_in[17];
    const float* bq1 = (const float*)d_in[18];
    const float* Wq2 = (const float*)d_in[19];
    const float* bq2 = (const float*)d_in[20];

    float* out = (float*)d_out;
    float* out_q = out;                 // B*N*4
    float* out_x = out + 4096;          // B*N*3
    float* out_o = out + 7168;          // B*N*64

    float* ws    = (float*)d_ws;
    short* wbf   = (short*)(ws + WS_WBF);
    float* ngeo  = ws + WS_NGEO;
    float* Apre  = ws + WS_APRE;
    float* BpreF = ws + WS_BPREF;
    float* mpart = ws + WS_MPART;
    float* dxbuf = ws + WS_DXBUF;

    k_prep<<<dim3(23), dim3(256), 0, stream>>>(Wm1, Wm2, Wt1, Wt2, wbf);

    k_node_pre<<<dim3(B_ * N_ / 4), dim3(256), 0, stream>>>(
        x, quats, h, Wm1, bm1, ngeo, Apre, BpreF);

    k_edge<<<dim3(512), dim3(512), 0, stream>>>(
        e, ngeo, Apre, BpreF, wbf, bm2, bt1, bt2, mpart, dxbuf);

    k_node_post<<<dim3(B_ * N_ / 4), dim3(256), 0, stream>>>(
        quats, h, mpart, Wf1, bf1, Wf2, bf2, Wq1, bq1, Wq2, bq2,
        out_q, out_o);

    k_aggregate<<<dim3(B_ * N_), dim3(256), 0, stream>>>(
        x, out_q, dxbuf, out_x);
}

// Round 10
// 175.308 us; speedup vs baseline: 1.4611x; 1.4611x over previous
//
#include <hip/hip_runtime.h>
#include <math.h>
#include <stdint.h>

#define B_ 2
#define N_ 512

// ws layout (float offsets)
#define WS_WBF   0            // 14976 shorts = 7488 floats, pad 7680
#define WS_NGEO  7680         // B*N*8      = 8192   {x0,x1,x2,0, qw,qx,qy,qz}
#define WS_APRE  15872        // B*N*64     = 65536  (bm1 folded in)
#define WS_BPREF 81408        // B*N*64     = 65536  (MFMA-fragment order)
#define WS_MPART 146944       // 2*B*N*64   = 131072
#define WS_DXBUF 278016       // B*N*N*4    = 2097152  (total 2375168 floats)

typedef short short8v __attribute__((ext_vector_type(8)));
typedef float f32x4 __attribute__((ext_vector_type(4)));

union FragU { int4 i; short8v s; };
union PackU { uint32_t w[4]; short8v s; };

static __device__ inline uint32_t pk2(float lo, float hi) {
    uint32_t r;
    asm volatile("v_cvt_pk_bf16_f32 %0, %1, %2" : "=v"(r) : "v"(lo), "v"(hi));
    return r;
}
static __device__ inline short f2bs(float f) {  // RNE f32->bf16
    uint32_t u = __float_as_uint(f);
    u = (u + 0x7FFFu + ((u >> 16) & 1u)) >> 16;
    return (short)u;
}

// ---------------------------------------------------------------------------
// Kernel P: one-time weight permute+bf16 into ws (layout == k_edge LDS):
//   [0,4608)=W1', [4608,9216)=W2', [9216,13824)=W3', [13824,14976)=W4'
// grid: 23 blocks x 256
// ---------------------------------------------------------------------------
__global__ void k_prep(const float* __restrict__ Wm1, const float* __restrict__ Wm2,
                       const float* __restrict__ Wt1, const float* __restrict__ Wt2,
                       short* __restrict__ wbf)
{
    const int id = blockIdx.x * 256 + threadIdx.x;
    if (id < 4608) {
        const int ch = id / 72, p = id % 72;
        float v1 = 0.f, v2 = 0.f, v3 = 0.f;
        if (p < 64) {
            if (p < 32) v1 = Wm1[(128 + p) * 64 + ch];
            else if (p < 41) v1 = Wm1[(160 + p - 32) * 64 + ch];
            const int s = p >> 5, ee = p & 7, gg = (p >> 3) & 3;
            const int k1 = 32 * s + 16 * (ee >> 2) + 4 * gg + (ee & 3);
            v2 = Wm2[k1 * 64 + ch];
            v3 = Wt1[k1 * 64 + ch];
        }
        wbf[id] = f2bs(v1);
        wbf[4608 + id] = f2bs(v2);
        wbf[9216 + id] = f2bs(v3);
    } else if (id < 5760) {
        const int idx = id - 4608;
        const int d = idx / 72, p = idx % 72;
        float v = 0.f;
        if (p < 64 && d < 3) {
            const int s = p >> 5, ee = p & 7, gg = (p >> 3) & 3;
            const int k1 = 32 * s + 16 * (ee >> 2) + 4 * gg + (ee & 3);
            v = Wt2[k1 * 3 + d];
        }
        wbf[13824 + idx] = f2bs(v);
    }
}

// ---------------------------------------------------------------------------
// Kernel 0: per-node precompute (unchanged).
// ---------------------------------------------------------------------------
__global__ __launch_bounds__(256) void k_node_pre(
    const float* __restrict__ x,
    const float* __restrict__ quats,
    const float* __restrict__ h,
    const float* __restrict__ Wm1,
    const float* __restrict__ bm1,
    float* __restrict__ ngeo,
    float* __restrict__ Apre,
    float* __restrict__ BpreF)
{
    __shared__ float sW[128 * 64];
    __shared__ float sh[4][64];

    const int tid = threadIdx.x;
    for (int idx = tid; idx < 128 * 64 / 4; idx += 256)
        ((float4*)sW)[idx] = ((const float4*)Wm1)[idx];

    const int wv = tid >> 6;
    const int c = tid & 63;
    const int node = blockIdx.x * 4 + wv;

    sh[wv][c] = h[node * 64 + c];
    __syncthreads();

    float a = bm1[c];
    float bv = 0.f;
#pragma unroll 8
    for (int k = 0; k < 64; ++k) {
        const float hk = sh[wv][k];
        a  = fmaf(hk, sW[k * 64 + c], a);
        bv = fmaf(hk, sW[(64 + k) * 64 + c], bv);
    }
    Apre[node * 64 + c] = a;
    const int aa = c >> 4, gg = (c >> 2) & 3, bb = c & 3;
    BpreF[(node >> 4) * 1024 + ((node & 15) + 16 * gg) * 16 + 4 * aa + bb] = bv;

    if (c == 0) {
        ngeo[node * 8 + 0] = x[node * 3 + 0];
        ngeo[node * 8 + 1] = x[node * 3 + 1];
        ngeo[node * 8 + 2] = x[node * 3 + 2];
        ngeo[node * 8 + 3] = 0.f;
        ngeo[node * 8 + 4] = quats[node * 4 + 0];
        ngeo[node * 8 + 5] = quats[node * 4 + 1];
        ngeo[node * 8 + 6] = quats[node * 4 + 2];
        ngeo[node * 8 + 7] = quats[node * 4 + 3];
    }
}

// ---------------------------------------------------------------------------
// Kernel A: MFMA edge pipeline. 512 blocks x 512 threads (8 waves).
// __launch_bounds__(512, 2): 2 blocks/CU x 8 waves = 16 waves/CU,
// VGPR cap 128 >= ~84 needed -> NO SPILLS (round-8 (512,4) forced 64 VGPR
// and spilled ~185 MB of scratch traffic per dispatch).
// ---------------------------------------------------------------------------
__global__ __launch_bounds__(512, 2) void k_edge(
    const float* __restrict__ e,
    const float* __restrict__ ngeo,
    const float* __restrict__ Apre,
    const float* __restrict__ BpreF,
    const short* __restrict__ wbf,
    const float* __restrict__ bm2,
    const float* __restrict__ bt1,
    const float* __restrict__ bt2,
    float* __restrict__ mpart, float* __restrict__ dxbuf)
{
    __shared__ __align__(16) short Ws[14976];
    __shared__ float msLDS[4][64];

    const int tid = threadIdx.x;

    for (int idx = tid; idx < 1872; idx += 512)
        ((int4*)Ws)[idx] = ((const int4*)wbf)[idx];
    __syncthreads();

    const short* W1s = Ws;
    const short* W2s = Ws + 4608;
    const short* W3s = Ws + 9216;
    const short* W4s = Ws + 13824;

    const int w = tid >> 6;
    const int l = tid & 63;
    const int g = l >> 4;
    const int c = l & 15;

    const int ig = blockIdx.x >> 1;
    const int half = blockIdx.x & 1;
    const int ni = ig * 4 + (w >> 1);   // 0..1023
    const int b = ni >> 9;
    const int i = ni & 511;
    const int quarter = half * 2 + (w & 1);
    const int j0w = quarter * 128;

    // i-node data
    const float4 gi0 = ((const float4*)ngeo)[ni * 2 + 0];
    const float4 gi1 = ((const float4*)ngeo)[ni * 2 + 1];
    const float xi0 = gi0.x, xi1 = gi0.y, xi2 = gi0.z;
    const float qi0 = gi1.x, qi1 = gi1.y, qi2 = gi1.z, qi3 = gi1.w;

    float apre[16], bm2r[16], bt1r[16], bt2r[4];
#pragma unroll
    for (int q = 0; q < 16; ++q) {
        const int row = 16 * (q >> 2) + 4 * g + (q & 3);
        apre[q] = Apre[ni * 64 + row];
        bm2r[q] = bm2[row];
        bt1r[q] = bt1[row];
    }
#pragma unroll
    for (int q = 0; q < 4; ++q) {
        const int d = 4 * g + q;
        bt2r[q] = (d < 3) ? bt2[d] : 0.f;
    }

    float msum[16];
#pragma unroll
    for (int q = 0; q < 16; ++q) msum[q] = 0.f;

#pragma unroll 2
    for (int t = 0; t < 8; ++t) {
        const int j0m = j0w + t * 16;
        const int nj = b * N_ + j0m + c;

        // ---- all global loads issued up front ----
        const float* ep = e + ((size_t)(b * N_ + i) * N_ + j0m + c) * 32 + g * 8;
        const float4 e0 = *(const float4*)ep;
        const float4 e1 = *(const float4*)(ep + 4);
        const float4 n0 = ((const float4*)ngeo)[nj * 2 + 0];
        const float4 n1 = ((const float4*)ngeo)[nj * 2 + 1];
        const float* bp = BpreF + (size_t)(nj >> 4) * 1024 + l * 16;
        const float4 bi0 = ((const float4*)bp)[0];
        const float4 bi1 = ((const float4*)bp)[1];
        const float4 bi2 = ((const float4*)bp)[2];
        const float4 bi3 = ((const float4*)bp)[3];

        // ---- geometry for edge (i, j0m+c), in registers ----
        const float xj0 = n0.x, xj1 = n0.y, xj2 = n0.z;
        const float qj0 = n1.x, qj1 = n1.y, qj2 = n1.z, qj3 = n1.w;
        const float dsum = qj0 * qj0 + qj1 * qj1 + qj2 * qj2 + qj3 * qj3;
        const float inv = __builtin_amdgcn_rcpf(dsum);
        const float qw = qj0 * inv, qx = -qj1 * inv;
        const float qy = -qj2 * inv, qz = -qj3 * inv;
        const float d0 = xi0 - xj0, d1 = xi1 - xj1, d2v = xi2 - xj2;
        const float dd = d0 * d0 + d1 * d1 + d2v * d2v;
        const float qd = fabsf(qi0 * qj0 + qi1 * qj1 + qi2 * qj2 + qi3 * qj3);
        const float ww = qw * qw, xx = qx * qx, yy = qy * qy, zz = qz * qz;
        const float xy = qx * qy, xz = qx * qz, yz = qy * qz;
        const float wx = qw * qx, wy = qw * qy, wz = qw * qz;
        const float lx0 = (ww + xx - yy - zz) * d0 + 2.f * (xy - wz) * d1 + 2.f * (xz + wy) * d2v;
        const float lx1 = 2.f * (xy + wz) * d0 + (ww - xx + yy - zz) * d1 + 2.f * (yz - wx) * d2v;
        const float lx2 = 2.f * (xz - wy) * d0 + 2.f * (yz + wx) * d1 + (ww - xx - yy + zz) * d2v;
        const float lq0 = qw * qi0 - qx * qi1 - qy * qi2 - qz * qi3;
        const float lq1 = qw * qi1 + qx * qi0 + qy * qi3 - qz * qi2;
        const float lq2 = qw * qi2 - qx * qi3 + qy * qi0 + qz * qi1;
        const float lq3 = qw * qi3 + qx * qi2 - qy * qi1 + qz * qi0;

        // ---- build S1 B-operand frags in registers ----
        PackU y0, yg;
        y0.w[0] = pk2(e0.x, e0.y); y0.w[1] = pk2(e0.z, e0.w);
        y0.w[2] = pk2(e1.x, e1.y); y0.w[3] = pk2(e1.z, e1.w);
        const uint32_t w0 = pk2(lx0, lx1), w1 = pk2(lx2, lq0);
        const uint32_t w2 = pk2(lq1, lq2), w3 = pk2(lq3, dd);
        const uint32_t wq = pk2(qd, 0.f);
        yg.w[0] = (g == 0) ? w0 : ((g == 1) ? wq : 0u);
        yg.w[1] = (g == 0) ? w1 : 0u;
        yg.w[2] = (g == 0) ? w2 : 0u;
        yg.w[3] = (g == 0) ? w3 : 0u;

        // ---- S1: m1T = relu(W1' x feat + Apre + Bpre) ----
        f32x4 acc1[4];
        acc1[0][0] = apre[0] + bi0.x;  acc1[0][1] = apre[1] + bi0.y;
        acc1[0][2] = apre[2] + bi0.z;  acc1[0][3] = apre[3] + bi0.w;
        acc1[1][0] = apre[4] + bi1.x;  acc1[1][1] = apre[5] + bi1.y;
        acc1[1][2] = apre[6] + bi1.z;  acc1[1][3] = apre[7] + bi1.w;
        acc1[2][0] = apre[8] + bi2.x;  acc1[2][1] = apre[9] + bi2.y;
        acc1[2][2] = apre[10] + bi2.z; acc1[2][3] = apre[11] + bi2.w;
        acc1[3][0] = apre[12] + bi3.x; acc1[3][1] = apre[13] + bi3.y;
        acc1[3][2] = apre[14] + bi3.z; acc1[3][3] = apre[15] + bi3.w;
#pragma unroll
        for (int nt = 0; nt < 4; ++nt) {
            FragU xw0, xw1;
            xw0.i = *(const int4*)&W1s[(16 * nt + c) * 72 + g * 8];
            xw1.i = *(const int4*)&W1s[(16 * nt + c) * 72 + 32 + g * 8];
            acc1[nt] = __builtin_amdgcn_mfma_f32_16x16x32_bf16(xw0.s, y0.s, acc1[nt], 0, 0, 0);
            acc1[nt] = __builtin_amdgcn_mfma_f32_16x16x32_bf16(xw1.s, yg.s, acc1[nt], 0, 0, 0);
        }

        PackU by1[2];
#pragma unroll
        for (int s = 0; s < 2; ++s) {
            const f32x4 a0 = acc1[2 * s], a1 = acc1[2 * s + 1];
            by1[s].w[0] = pk2(fmaxf(a0[0], 0.f), fmaxf(a0[1], 0.f));
            by1[s].w[1] = pk2(fmaxf(a0[2], 0.f), fmaxf(a0[3], 0.f));
            by1[s].w[2] = pk2(fmaxf(a1[0], 0.f), fmaxf(a1[1], 0.f));
            by1[s].w[3] = pk2(fmaxf(a1[2], 0.f), fmaxf(a1[3], 0.f));
        }

        // ---- S2: mT = W2' x m1 + bm2 ----
        f32x4 acc2[4];
#pragma unroll
        for (int nt = 0; nt < 4; ++nt) {
            acc2[nt][0] = bm2r[nt * 4 + 0]; acc2[nt][1] = bm2r[nt * 4 + 1];
            acc2[nt][2] = bm2r[nt * 4 + 2]; acc2[nt][3] = bm2r[nt * 4 + 3];
        }
#pragma unroll
        for (int nt = 0; nt < 4; ++nt)
#pragma unroll
            for (int s = 0; s < 2; ++s) {
                FragU xw;
                xw.i = *(const int4*)&W2s[(16 * nt + c) * 72 + s * 32 + g * 8];
                acc2[nt] = __builtin_amdgcn_mfma_f32_16x16x32_bf16(
                    xw.s, by1[s].s, acc2[nt], 0, 0, 0);
            }

        const float maskf = (j0m + c == i) ? 0.f : 1.f;
#pragma unroll
        for (int nt = 0; nt < 4; ++nt) {
            acc2[nt][0] *= maskf; acc2[nt][1] *= maskf;
            acc2[nt][2] *= maskf; acc2[nt][3] *= maskf;
            msum[nt * 4 + 0] += acc2[nt][0];
            msum[nt * 4 + 1] += acc2[nt][1];
            msum[nt * 4 + 2] += acc2[nt][2];
            msum[nt * 4 + 3] += acc2[nt][3];
        }

        PackU by2[2];
#pragma unroll
        for (int s = 0; s < 2; ++s) {
            const f32x4 a0 = acc2[2 * s], a1 = acc2[2 * s + 1];
            by2[s].w[0] = pk2(a0[0], a0[1]);
            by2[s].w[1] = pk2(a0[2], a0[3]);
            by2[s].w[2] = pk2(a1[0], a1[1]);
            by2[s].w[3] = pk2(a1[2], a1[3]);
        }

        // ---- S3: t1T = relu(W3' x m + bt1) ----
        f32x4 acc3[4];
#pragma unroll
        for (int nt = 0; nt < 4; ++nt) {
            acc3[nt][0] = bt1r[nt * 4 + 0]; acc3[nt][1] = bt1r[nt * 4 + 1];
            acc3[nt][2] = bt1r[nt * 4 + 2]; acc3[nt][3] = bt1r[nt * 4 + 3];
        }
#pragma unroll
        for (int nt = 0; nt < 4; ++nt)
#pragma unroll
            for (int s = 0; s < 2; ++s) {
                FragU xw;
                xw.i = *(const int4*)&W3s[(16 * nt + c) * 72 + s * 32 + g * 8];
                acc3[nt] = __builtin_amdgcn_mfma_f32_16x16x32_bf16(
                    xw.s, by2[s].s, acc3[nt], 0, 0, 0);
            }

        PackU by3[2];
#pragma unroll
        for (int s = 0; s < 2; ++s) {
            const f32x4 a0 = acc3[2 * s], a1 = acc3[2 * s + 1];
            by3[s].w[0] = pk2(fmaxf(a0[0], 0.f), fmaxf(a0[1], 0.f));
            by3[s].w[1] = pk2(fmaxf(a0[2], 0.f), fmaxf(a0[3], 0.f));
            by3[s].w[2] = pk2(fmaxf(a1[0], 0.f), fmaxf(a1[1], 0.f));
            by3[s].w[3] = pk2(fmaxf(a1[2], 0.f), fmaxf(a1[3], 0.f));
        }

        // ---- dx: rows 0..2 of W4' x t1 + bt2 ----
        f32x4 acc4;
        acc4[0] = bt2r[0]; acc4[1] = bt2r[1]; acc4[2] = bt2r[2]; acc4[3] = bt2r[3];
#pragma unroll
        for (int s = 0; s < 2; ++s) {
            FragU xw;
            xw.i = *(const int4*)&W4s[c * 72 + s * 32 + g * 8];
            acc4 = __builtin_amdgcn_mfma_f32_16x16x32_bf16(
                xw.s, by3[s].s, acc4, 0, 0, 0);
        }
        if (g == 0) {
            float4 o4;
            o4.x = acc4[0] * maskf; o4.y = acc4[1] * maskf;
            o4.z = acc4[2] * maskf; o4.w = 0.f;
            ((float4*)dxbuf)[(size_t)ni * N_ + j0m + c] = o4;
        }
    }

    // ---- msum: xor-reduce over c, combine wave pairs in LDS, store halves ----
#pragma unroll
    for (int q = 0; q < 16; ++q) {
        float v = msum[q];
        v += __shfl_xor(v, 1); v += __shfl_xor(v, 2);
        v += __shfl_xor(v, 4); v += __shfl_xor(v, 8);
        msum[q] = v;
    }
    __syncthreads();
    if ((w & 1) && c == 0) {
#pragma unroll
        for (int q = 0; q < 16; ++q)
            msLDS[w >> 1][16 * (q >> 2) + 4 * g + (q & 3)] = msum[q];
    }
    __syncthreads();
    if (!(w & 1) && c == 0) {
#pragma unroll
        for (int nt = 0; nt < 4; ++nt) {
            float4 mo;
            mo.x = msum[nt * 4 + 0] + msLDS[w >> 1][16 * nt + 4 * g + 0];
            mo.y = msum[nt * 4 + 1] + msLDS[w >> 1][16 * nt + 4 * g + 1];
            mo.z = msum[nt * 4 + 2] + msLDS[w >> 1][16 * nt + 4 * g + 2];
            mo.w = msum[nt * 4 + 3] + msLDS[w >> 1][16 * nt + 4 * g + 3];
            *(float4*)&mpart[((size_t)(half * (B_ * N_) + ni)) * 64 + 16 * nt + 4 * g] = mo;
        }
    }
}

// ---------------------------------------------------------------------------
// Kernel B: per-node outputs (2 mpart halves).
// ---------------------------------------------------------------------------
__global__ __launch_bounds__(256) void k_node_post(
    const float* __restrict__ quats,
    const float* __restrict__ h,
    const float* __restrict__ mpart,
    const float* __restrict__ Wf1, const float* __restrict__ bf1,
    const float* __restrict__ Wf2, const float* __restrict__ bf2,
    const float* __restrict__ Wq1, const float* __restrict__ bq1,
    const float* __restrict__ Wq2, const float* __restrict__ bq2,
    float* __restrict__ out_q, float* __restrict__ out_o)
{
    __shared__ float sWf1[128 * 64];
    __shared__ float sWf2[64 * 64];
    __shared__ float sWq1[64 * 64];
    __shared__ float sWq2[64 * 4];
    __shared__ float sh[4][64], sm[4][64], stf[4][64], stq[4][64];

    const int tid = threadIdx.x;
    for (int idx = tid; idx < 128 * 64 / 4; idx += 256)
        ((float4*)sWf1)[idx] = ((const float4*)Wf1)[idx];
    for (int idx = tid; idx < 64 * 64 / 4; idx += 256) {
        ((float4*)sWf2)[idx] = ((const float4*)Wf2)[idx];
        ((float4*)sWq1)[idx] = ((const float4*)Wq1)[idx];
    }
    if (tid < 64) {
        sWq2[tid * 4 + 0] = Wq2[tid * 4 + 0];
        sWq2[tid * 4 + 1] = Wq2[tid * 4 + 1];
        sWq2[tid * 4 + 2] = Wq2[tid * 4 + 2];
        sWq2[tid * 4 + 3] = Wq2[tid * 4 + 3];
    }

    const int wv = tid >> 6;
    const int c = tid & 63;
    const int node = blockIdx.x * 4 + wv;

    const float ms = mpart[(size_t)node * 64 + c] +
                     mpart[((size_t)(B_ * N_) + node) * 64 + c];
    sm[wv][c] = ms;
    sh[wv][c] = h[node * 64 + c];
    __syncthreads();

    float accf = bf1[c];
    float accq = bq1[c];
#pragma unroll 8
    for (int k = 0; k < 64; ++k) {
        const float hk = sh[wv][k];
        const float mk = sm[wv][k];
        accf = fmaf(hk, sWf1[k * 64 + c], accf);
        accf = fmaf(mk, sWf1[(64 + k) * 64 + c], accf);
        accq = fmaf(mk, sWq1[k * 64 + c], accq);
    }
    stf[wv][c] = fmaxf(accf, 0.f);
    stq[wv][c] = fmaxf(accq, 0.f);
    __syncthreads();

    float o = bf2[c];
#pragma unroll 8
    for (int k = 0; k < 64; ++k) o = fmaf(stf[wv][k], sWf2[k * 64 + c], o);
    out_o[(size_t)node * 64 + c] = o;

    {
        const int d = c & 3, kb = c >> 2;
        float p = 0.f;
#pragma unroll
        for (int m = 0; m < 4; ++m) {
            const int kk = kb + 16 * m;
            p = fmaf(stq[wv][kk], sWq2[kk * 4 + d], p);
        }
        p += __shfl_xor(p, 4);  p += __shfl_xor(p, 8);
        p += __shfl_xor(p, 16); p += __shfl_xor(p, 32);
        const float p0 = __shfl(p, 0), p1 = __shfl(p, 1);
        const float p2 = __shfl(p, 2), p3 = __shfl(p, 3);
        if (c == 0) {
            float dq0 = p0 + bq2[0], dq1 = p1 + bq2[1];
            float dq2 = p2 + bq2[2], dq3 = p3 + bq2[3];
            const float nrm = sqrtf(dq0 * dq0 + dq1 * dq1 + dq2 * dq2 + dq3 * dq3);
            const float inv = 1.f / fmaxf(nrm, 1e-12f);
            const float b0 = dq0 * inv, b1 = dq1 * inv, b2 = dq2 * inv, b3 = dq3 * inv;
            const float aw = quats[node * 4 + 0], ax = quats[node * 4 + 1];
            const float ay = quats[node * 4 + 2], az = quats[node * 4 + 3];
            float u0 = aw * b0 - ax * b1 - ay * b2 - az * b3;
            float u1 = aw * b1 + ax * b0 + ay * b3 - az * b2;
            float u2 = aw * b2 - ax * b3 + ay * b0 + az * b1;
            float u3 = aw * b3 + ax * b2 - ay * b1 + az * b0;
            const float n2 = sqrtf(u0 * u0 + u1 * u1 + u2 * u2 + u3 * u3);
            u0 /= n2; u1 /= n2; u2 /= n2; u3 /= n2;
            out_q[node * 4 + 0] = u0; out_q[node * 4 + 1] = u1;
            out_q[node * 4 + 2] = u2; out_q[node * 4 + 3] = u3;
        }
    }
}

// ---------------------------------------------------------------------------
// Kernel C: upd_x[i] = x_i + (sum_j R(out_q_j) dx[i,j]) / (N-1)
// ---------------------------------------------------------------------------
__global__ void k_aggregate(const float* __restrict__ x,
                            const float* __restrict__ out_q,
                            const float* __restrict__ dxbuf,
                            float* __restrict__ out_x)
{
    const int node = blockIdx.x;
    const int b = node >> 9;
    const int tid = threadIdx.x;

    float s0 = 0.f, s1 = 0.f, s2 = 0.f;
    for (int j = tid; j < N_; j += 256) {
        const float4 d4 = ((const float4*)dxbuf)[(size_t)node * N_ + j];
        const float4 q4 = ((const float4*)out_q)[b * N_ + j];
        const float w = q4.x, X = q4.y, Y = q4.z, Z = q4.w;
        const float ww = w * w, xx = X * X, yy = Y * Y, zz = Z * Z;
        const float xy = X * Y, xz = X * Z, yz = Y * Z;
        const float wx = w * X, wy = w * Y, wz = w * Z;
        s0 += (ww + xx - yy - zz) * d4.x + 2.f * (xy - wz) * d4.y + 2.f * (xz + wy) * d4.z;
        s1 += 2.f * (xy + wz) * d4.x + (ww - xx + yy - zz) * d4.y + 2.f * (yz - wx) * d4.z;
        s2 += 2.f * (xz - wy) * d4.x + 2.f * (yz + wx) * d4.y + (ww - xx - yy + zz) * d4.z;
    }
#pragma unroll
    for (int off = 1; off <= 32; off <<= 1) {
        s0 += __shfl_xor(s0, off);
        s1 += __shfl_xor(s1, off);
        s2 += __shfl_xor(s2, off);
    }
    __shared__ float red[4][3];
    const int wave = tid >> 6, lane = tid & 63;
    if (lane == 0) { red[wave][0] = s0; red[wave][1] = s1; red[wave][2] = s2; }
    __syncthreads();
    if (tid == 0) {
        const float t0 = red[0][0] + red[1][0] + red[2][0] + red[3][0];
        const float t1 = red[0][1] + red[1][1] + red[2][1] + red[3][1];
        const float t2 = red[0][2] + red[1][2] + red[2][2] + red[3][2];
        const float inv = 1.f / (float)(N_ - 1);
        out_x[node * 3 + 0] = x[node * 3 + 0] + t0 * inv;
        out_x[node * 3 + 1] = x[node * 3 + 1] + t1 * inv;
        out_x[node * 3 + 2] = x[node * 3 + 2] + t2 * inv;
    }
}

// ---------------------------------------------------------------------------
extern "C" void kernel_launch(void* const* d_in, const int* in_sizes, int n_in,
                              void* d_out, int out_size, void* d_ws, size_t ws_size,
                              hipStream_t stream) {
    const float* x     = (const float*)d_in[0];
    const float* quats = (const float*)d_in[1];
    const float* h     = (const float*)d_in[2];
    const float* e     = (const float*)d_in[3];
    const float* Wm1 = (const float*)d_in[5];
    const float* bm1 = (const float*)d_in[6];
    const float* Wm2 = (const float*)d_in[7];
    const float* bm2 = (const float*)d_in[8];
    const float* Wf1 = (const float*)d_in[9];
    const float* bf1 = (const float*)d_in[10];
    const float* Wf2 = (const float*)d_in[11];
    const float* bf2 = (const float*)d_in[12];
    const float* Wt1 = (const float*)d_in[13];
    const float* bt1 = (const float*)d_in[14];
    const float* Wt2 = (const float*)d_in[15];
    const float* bt2 = (const float*)d_in[16];
    const float* Wq1 = (const float*)d_in[17];
    const float* bq1 = (const float*)d_in[18];
    const float* Wq2 = (const float*)d_in[19];
    const float* bq2 = (const float*)d_in[20];

    float* out = (float*)d_out;
    float* out_q = out;                 // B*N*4
    float* out_x = out + 4096;          // B*N*3
    float* out_o = out + 7168;          // B*N*64

    float* ws    = (float*)d_ws;
    short* wbf   = (short*)(ws + WS_WBF);
    float* ngeo  = ws + WS_NGEO;
    float* Apre  = ws + WS_APRE;
    float* BpreF = ws + WS_BPREF;
    float* mpart = ws + WS_MPART;
    float* dxbuf = ws + WS_DXBUF;

    k_prep<<<dim3(23), dim3(256), 0, stream>>>(Wm1, Wm2, Wt1, Wt2, wbf);

    k_node_pre<<<dim3(B_ * N_ / 4), dim3(256), 0, stream>>>(
        x, quats, h, Wm1, bm1, ngeo, Apre, BpreF);

    k_edge<<<dim3(512), dim3(512), 0, stream>>>(
        e, ngeo, Apre, BpreF, wbf, bm2, bt1, bt2, mpart, dxbuf);

    k_node_post<<<dim3(B_ * N_ / 4), dim3(256), 0, stream>>>(
        quats, h, mpart, Wf1, bf1, Wf2, bf2, Wq1, bq1, Wq2, bq2,
        out_q, out_o);

    k_aggregate<<<dim3(B_ * N_), dim3(256), 0, stream>>>(
        x, out_q, dxbuf, out_x);
}